// Round 2
// baseline (2263.350 us; speedup 1.0000x reference)
//
#include <hip/hip_runtime.h>

#define H_ 48
#define W_ 176
#define HW_ 8448
#define K_ 8449
#define C_ 256
#define KD_ 64
#define PSM_SZ 33792
#define RM_SZ 236544

typedef _Float16 f16x8 __attribute__((ext_vector_type(8)));
typedef float f32x4 __attribute__((ext_vector_type(4)));

// ---------------- weight transposes (run once per call, tiny) ----------------
__global__ void transpose_w(const float* __restrict__ qw, const float* __restrict__ qkw,
                            const float* __restrict__ kw, float* __restrict__ qT,
                            float* __restrict__ qkT, float* __restrict__ kT) {
  int b = blockIdx.x, t = threadIdx.x;
  if (b < 256)      qT[t*256 + b]        = qw[b*256 + t];        // qT[c][o]
  else if (b < 320) qkT[t*64 + (b-256)]  = qkw[(b-256)*256 + t]; // qkT[o][j]
  else              kT[t*64 + (b-320)]   = kw[(b-320)*256 + t];  // kT[c][j]
}

// ---------------- hidden = relu(q_w @ feat + q_b), imgs 0,2 ----------------
__global__ __launch_bounds__(256) void gemm_hidden(
    const float* __restrict__ feats, const float* __restrict__ qT,
    const float* __restrict__ qb, float* __restrict__ hidden) {
  __shared__ float ldsW[32*132];
  __shared__ float ldsF[32*64];
  const int t = threadIdx.x;
  const int px0 = blockIdx.x * 64;
  const int ob = blockIdx.y * 128;
  const int slot = blockIdx.z;       // 0,1 -> imgs 0,2
  const int img = slot * 2;
  const int pg = t & 15, og = t >> 4;
  float acc[32];
  #pragma unroll
  for (int z = 0; z < 32; z++) acc[z] = 0.f;
  const float* fbase = feats + (size_t)img*C_*HW_ + px0;
  for (int cb = 0; cb < 256; cb += 32) {
    for (int e = t; e < 2048; e += 256) {
      int cc = e >> 6, px = e & 63;
      ldsF[cc*64 + px] = fbase[(size_t)(cb+cc)*HW_ + px];
    }
    for (int e = t; e < 4096; e += 256) {
      int cc = e >> 7, o = e & 127;
      ldsW[cc*132 + o] = qT[(size_t)(cb+cc)*256 + ob + o];
    }
    __syncthreads();
    #pragma unroll 4
    for (int cc = 0; cc < 32; cc++) {
      f32x4 fv = *(const f32x4*)&ldsF[cc*64 + pg*4];
      f32x4 w0 = *(const f32x4*)&ldsW[cc*132 + og*8];
      f32x4 w1 = *(const f32x4*)&ldsW[cc*132 + og*8 + 4];
      #pragma unroll
      for (int p = 0; p < 4; p++) {
        float f = fv[p];
        #pragma unroll
        for (int q = 0; q < 4; q++) {
          acc[q*4+p]     += w0[q]*f;
          acc[(4+q)*4+p] += w1[q]*f;
        }
      }
    }
    __syncthreads();
  }
  float* hbase = hidden + (size_t)slot*C_*HW_;
  #pragma unroll
  for (int q = 0; q < 8; q++) {
    int o = ob + og*8 + q;
    float b = qb[o];
    f32x4 ov;
    #pragma unroll
    for (int p = 0; p < 4; p++) {
      float v = acc[q*4+p] + b;
      ov[p] = v > 0.f ? v : 0.f;
    }
    *(f32x4*)&hbase[(size_t)o*HW_ + px0 + pg*4] = ov;
  }
}

// ---------------- 64-out GEMM: MODE0 = qk (querys), MODE1 = keys ----------------
template<int MODE>
__global__ __launch_bounds__(256) void gemm_small(
    const float* __restrict__ inp, const float* __restrict__ wT,
    const float* __restrict__ bias, _Float16* __restrict__ out16,
    _Float16* __restrict__ f2h, float* __restrict__ qnormNeg) {
  __shared__ float ldsI[64*64];
  __shared__ float ldsW2[64*68];
  __shared__ float red16[64*16];
  __shared__ float red32[64*16];
  const int t = threadIdx.x;
  const int px0 = blockIdx.x*64;
  const int i = blockIdx.y;
  const float* ibase = (MODE==0) ? (inp + (size_t)i*C_*HW_ + px0)
                                 : (inp + (size_t)(1+2*i)*C_*HW_ + px0);
  const int pg = t & 15, jg = t >> 4;
  float acc[16];
  #pragma unroll
  for (int z=0;z<16;z++) acc[z]=0.f;
  for (int ob = 0; ob < 256; ob += 64) {
    for (int e=t; e<4096; e+=256) { int oc=e>>6, px=e&63; ldsI[oc*64+px]=ibase[(size_t)(ob+oc)*HW_+px]; }
    for (int e=t; e<4096; e+=256) { int oc=e>>6, j=e&63;  ldsW2[oc*68+j]=wT[(size_t)(ob+oc)*64+j]; }
    __syncthreads();
    #pragma unroll 4
    for (int oc=0; oc<64; oc++) {
      f32x4 iv = *(const f32x4*)&ldsI[oc*64+pg*4];
      f32x4 wv = *(const f32x4*)&ldsW2[oc*68+jg*4];
      #pragma unroll
      for (int j=0;j<4;j++)
        #pragma unroll
        for (int p=0;p<4;p++)
          acc[j*4+p] += wv[j]*iv[p];
    }
    __syncthreads();
  }
  const int j0 = jg*4;
  float s16[4] = {0,0,0,0};
  float s32[4] = {0,0,0,0};
  #pragma unroll
  for (int p=0;p<4;p++) {
    union { _Float16 h[4]; uint2 u; } uu;
    #pragma unroll
    for (int j=0;j<4;j++) {
      float v = acc[j*4+p] + bias[j0+j];
      if (MODE==1) v = v > 0.f ? v : 0.f;
      _Float16 h = (_Float16)v;
      uu.h[j] = h;
      _Float16 hh = h*h;            // fp16-rounded product (matches f16 elementwise mul)
      s16[p] += (float)hh;
      if (MODE==0) s32[p] += v*v;   // f32 norm for 'last' channel
    }
    size_t pix = (size_t)i*HW_ + px0 + pg*4 + p;
    *(uint2*)&out16[pix*64 + j0] = uu.u;
  }
  #pragma unroll
  for (int p=0;p<4;p++) {
    red16[(pg*4+p)*16 + jg] = s16[p];
    if (MODE==0) red32[(pg*4+p)*16 + jg] = s32[p];
  }
  __syncthreads();
  if (t < 64) {
    float a16=0.f, a32=0.f;
    #pragma unroll
    for (int g=0; g<16; g++){ a16 += red16[t*16+g]; if (MODE==0) a32 += red32[t*16+g]; }
    f2h[(size_t)i*HW_ + px0 + t] = (_Float16)a16;
    if (MODE==0) qnormNeg[(size_t)i*HW_ + px0 + t] = -sqrtf(a32);
  }
}

// ---------------- corr volume GEMM: raw[k][p] = -(f16)sqrt(max(d2,0)) ----------------
__global__ __launch_bounds__(256) void corr_gemm(
    const _Float16* __restrict__ q16, const _Float16* __restrict__ k16,
    const _Float16* __restrict__ fa2h, const _Float16* __restrict__ fb2h,
    float* __restrict__ raw, int pair, int kbase) {
  __shared__ _Float16 Kt[128*72];
  __shared__ _Float16 Qt[128*72];
  __shared__ _Float16 fa2s[128];
  __shared__ _Float16 fb2s[128];
  const int t = threadIdx.x;
  const int p0 = blockIdx.x*128;
  const int k0 = kbase + blockIdx.y*128;
  const _Float16* qb = q16 + ((size_t)pair*HW_ + p0)*64;
  const _Float16* kb = k16 + ((size_t)pair*HW_ + k0)*64;
  for (int e=t; e<1024; e+=256) {
    int row = e>>3, c8 = e&7;
    *(f16x8*)&Kt[row*72 + c8*8] = *(const f16x8*)&kb[(size_t)row*64 + c8*8];
    *(f16x8*)&Qt[row*72 + c8*8] = *(const f16x8*)&qb[(size_t)row*64 + c8*8];
  }
  if (t<128) { fa2s[t] = fa2h[(size_t)pair*HW_ + p0 + t];
               fb2s[t] = fb2h[(size_t)pair*HW_ + k0 + t]; }
  __syncthreads();
  const int w = t>>6, lane = t&63;
  const int wr = w>>1, wc = w&1;
  const int lr = lane&15, lk = lane>>4;
  f32x4 acc[4][4];
  #pragma unroll
  for (int m=0;m<4;m++)
    #pragma unroll
    for (int n=0;n<4;n++) acc[m][n] = (f32x4){0.f,0.f,0.f,0.f};
  #pragma unroll
  for (int ks=0; ks<2; ks++){
    f16x8 af[4], bf[4];
    #pragma unroll
    for (int m=0;m<4;m++) af[m] = *(const f16x8*)&Kt[(wr*64+m*16+lr)*72 + ks*32 + lk*8];
    #pragma unroll
    for (int n=0;n<4;n++) bf[n] = *(const f16x8*)&Qt[(wc*64+n*16+lr)*72 + ks*32 + lk*8];
    #pragma unroll
    for (int m=0;m<4;m++)
      #pragma unroll
      for (int n=0;n<4;n++)
        acc[m][n] = __builtin_amdgcn_mfma_f32_16x16x32_f16(af[m], bf[n], acc[m][n], 0,0,0);
  }
  #pragma unroll
  for (int m=0;m<4;m++){
    #pragma unroll
    for (int n=0;n<4;n++){
      int colL = wc*64 + n*16 + lr;
      _Float16 fa2 = fa2s[colL];
      #pragma unroll
      for (int r=0;r<4;r++){
        int rowL = wr*64 + m*16 + lk*4 + r;
        _Float16 fb2 = fb2s[rowL];
        _Float16 dh = (_Float16)acc[m][n][r];
        _Float16 d2 = (_Float16)(fa2 + fb2) - (_Float16)((_Float16)2.0f * dh);
        if (d2 < (_Float16)0.f) d2 = (_Float16)0.f;
        _Float16 sh = (_Float16)sqrtf((float)d2);
        raw[(size_t)(k0 - kbase + rowL)*HW_ + p0 + colL] = -(float)sh;
      }
    }
  }
}

__global__ void lastrow(const float* __restrict__ qn, float* __restrict__ raw,
                        int pair, int rowLocal) {
  int p = blockIdx.x*256 + threadIdx.x;
  if (p < HW_) raw[(size_t)rowLocal*HW_ + p] = qn[(size_t)pair*HW_ + p];
}

// ---------------- depthwise 3x3 smooth + bias + write corr + argmax/max reduce ----------------
#define KC_ 15
__global__ __launch_bounds__(256) void smooth_reduce(
    const float* __restrict__ raw, const float* __restrict__ smw,
    const float* __restrict__ smb, float* __restrict__ outCorr,
    unsigned long long* __restrict__ packed, int pair, int kbase, int krows) {
  __shared__ float L[KC_][1056];
  __shared__ float SW[KC_][9];
  __shared__ float SB[KC_];
  const int t = threadIdx.x;
  const int kl0 = blockIdx.x * KC_;
  const int h0 = blockIdx.y * 4;
  const int pstart = (h0-1)*W_;
  for (int kk=0; kk<KC_; kk++){
    int kl = kl0 + kk;
    bool kok = (kl < krows);
    const float* rrow = raw + (size_t)kl*HW_;
    for (int off=t; off<1056; off+=256){
      int p = pstart + off;
      float v = 0.f;
      if (kok && p >= 0 && p < HW_) v = rrow[p];
      L[kk][off] = v;
    }
  }
  if (t < KC_*9){
    int kk = t/9, e = t%9;
    int kg = kbase + kl0 + kk;
    SW[kk][e] = (kg <= HW_ && (kl0+kk) < krows) ? smw[(size_t)kg*9 + e] : 0.f;
  }
  if (t < KC_){
    int kg = kbase + kl0 + t;
    SB[t] = (kg <= HW_ && (kl0+t) < krows) ? smb[kg] : 0.f;
  }
  __syncthreads();
  float* ob = outCorr + (size_t)pair*K_*HW_;
  unsigned long long* pk = packed + (size_t)pair*HW_;
  for (int px = t; px < 704; px += 256){
    int hh = px / 176, ww = px % 176;
    int p = (h0+hh)*W_ + ww;
    int base = (hh+1)*176 + ww;
    bool wm = (ww > 0), wpl = (ww < W_-1);
    unsigned long long best = 0;
    for (int kk=0; kk<KC_; kk++){
      int kl = kl0 + kk;
      if (kl >= krows) break;
      int kg = kbase + kl;
      const float* Lr = L[kk];
      const float* sw = SW[kk];
      float ys = 0.f;
      {
        int b0 = base - 176;
        if (wm)  ys += Lr[b0-1]*sw[0];
                 ys += Lr[b0  ]*sw[1];
        if (wpl) ys += Lr[b0+1]*sw[2];
      }
      {
        if (wm)  ys += Lr[base-1]*sw[3];
                 ys += Lr[base  ]*sw[4];
        if (wpl) ys += Lr[base+1]*sw[5];
      }
      {
        int b2 = base + 176;
        if (wm)  ys += Lr[b2-1]*sw[6];
                 ys += Lr[b2  ]*sw[7];
        if (wpl) ys += Lr[b2+1]*sw[8];
      }
      float val = ys + SB[kk];
      ob[(size_t)kg*HW_ + p] = val;
      unsigned u = __float_as_uint(val);
      u = (u & 0x80000000u) ? ~u : (u | 0x80000000u);
      unsigned long long cand = ((unsigned long long)u << 32) | (unsigned)(0xFFFFFFFFu - (unsigned)kg);
      if (cand > best) best = cand;
    }
    atomicMax(&pk[p], best);
  }
}

// ---------------- grid_sample + fuse-max + psm/rm convs ----------------
__global__ __launch_bounds__(256) void finalize(
    const float* __restrict__ feats, const unsigned long long* __restrict__ packed,
    const float* __restrict__ clsw, const float* __restrict__ clsb,
    const float* __restrict__ regw, const float* __restrict__ regb,
    float* __restrict__ out) {
  __shared__ float fuse[256][32];
  __shared__ int tapO[4][32];
  __shared__ float tapW[4][32];
  __shared__ float wmulS[32];
  const int t = threadIdx.x;
  const int b = blockIdx.y;
  const int px0 = blockIdx.x*32;
  if (t < 32) {
    int p = px0 + t;
    unsigned long long pkv = packed[(size_t)b*HW_ + p];
    unsigned u = (unsigned)(pkv >> 32);
    unsigned fbits = (u & 0x80000000u) ? (u ^ 0x80000000u) : ~u;
    float weight = __uint_as_float(fbits);
    int kg = (int)(0xFFFFFFFFu - (unsigned)(pkv & 0xFFFFFFFFu));
    bool mask = (kg == K_-1);
    int xi = mask ? 0 : (kg % W_);
    int yi = mask ? 0 : (kg / W_);
    float xn = 2.0f*((float)xi/176.0f - 0.5f);
    float yn = 2.0f*((float)yi/48.0f - 0.5f);
    float gx = (xn + 1.0f)*88.0f - 0.5f;
    float gy = (yn + 1.0f)*24.0f - 0.5f;
    float x0f = floorf(gx), y0f = floorf(gy);
    float wx = gx - x0f, wy = gy - y0f;
    int x0 = (int)x0f, y0 = (int)y0f;
    int ix[4] = {x0, x0+1, x0, x0+1};
    int iy[4] = {y0, y0, y0+1, y0+1};
    float tw[4] = {(1.f-wx)*(1.f-wy), wx*(1.f-wy), (1.f-wx)*wy, wx*wy};
    #pragma unroll
    for (int q=0;q<4;q++){
      bool valid = (ix[q]>=0 && ix[q]<W_ && iy[q]>=0 && iy[q]<H_);
      int cx = min(max(ix[q],0),W_-1), cy = min(max(iy[q],0),H_-1);
      tapO[q][t] = cy*W_ + cx;
      tapW[q][t] = valid ? tw[q] : 0.f;
    }
    wmulS[t] = mask ? weight : 0.f;
  }
  __syncthreads();
  const float* fA = feats + (size_t)(2*b)*C_*HW_;
  const float* fB = feats + (size_t)(2*b+1)*C_*HW_;
  const int px = t & 31, cg = t >> 5;
  const int p = px0 + px;
  const int o0=tapO[0][px], o1=tapO[1][px], o2=tapO[2][px], o3=tapO[3][px];
  const float w0=tapW[0][px], w1=tapW[1][px], w2=tapW[2][px], w3=tapW[3][px];
  const float wm = wmulS[px];
  for (int c = cg*32; c < cg*32+32; c++) {
    const float* fBc = fB + (size_t)c*HW_;
    float s = fBc[o0]*w0 + fBc[o1]*w1 + fBc[o2]*w2 + fBc[o3]*w3;
    fuse[c][px] = fmaxf(fA[(size_t)c*HW_ + p], s * wm);
  }
  __syncthreads();
  const int og = t >> 5;
  const int A0 = og*2, A1 = og*2+1;
  const float* r0 = (A0<2)? (clsw + A0*256) : (regw + (A0-2)*256);
  const float* r1 = (A1<2)? (clsw + A1*256) : (regw + (A1-2)*256);
  float a0 = 0.f, a1 = 0.f;
  for (int c=0;c<256;c++) {
    float f = fuse[c][px];
    a0 += f * r0[c];
    a1 += f * r1[c];
  }
  #pragma unroll
  for (int r=0;r<2;r++) {
    int a = og*2 + r;
    float v = (r==0?a0:a1) + ((a<2)? clsb[a] : regb[a-2]);
    size_t dst = (a<2) ? ((size_t)b*2*HW_ + (size_t)a*HW_ + p)
                       : ((size_t)PSM_SZ + (size_t)b*14*HW_ + (size_t)(a-2)*HW_ + p);
    out[dst] = v;
  }
}

// ---------------- launch ----------------
extern "C" void kernel_launch(void* const* d_in, const int* in_sizes, int n_in,
                              void* d_out, int out_size, void* d_ws, size_t ws_size,
                              hipStream_t stream) {
  const float* feats = (const float*)d_in[0];
  const float* q_w  = (const float*)d_in[1];
  const float* q_b  = (const float*)d_in[2];
  const float* qk_w = (const float*)d_in[3];
  const float* qk_b = (const float*)d_in[4];
  const float* k_w  = (const float*)d_in[5];
  const float* k_b  = (const float*)d_in[6];
  const float* sm_w = (const float*)d_in[7];
  const float* sm_b = (const float*)d_in[8];
  const float* cls_w= (const float*)d_in[9];
  const float* cls_b= (const float*)d_in[10];
  const float* reg_w= (const float*)d_in[11];
  const float* reg_b= (const float*)d_in[12];
  // d_in[13] = record_len; fixed [2,2] -> pairs (0,1),(2,3)

  char* wp = (char*)d_ws;
  auto alloc = [&](size_t bytes) { char* r = wp; wp += (bytes + 255) & ~(size_t)255; return r; };
  float* hidden   = (float*)alloc((size_t)2*C_*HW_*4);
  float* qT       = (float*)alloc((size_t)256*256*4);
  float* qkT      = (float*)alloc((size_t)256*64*4);
  float* kT       = (float*)alloc((size_t)256*64*4);
  _Float16* q16   = (_Float16*)alloc((size_t)2*HW_*64*2);
  _Float16* k16   = (_Float16*)alloc((size_t)2*HW_*64*2);
  _Float16* fa2h  = (_Float16*)alloc((size_t)2*HW_*2);
  _Float16* fb2h  = (_Float16*)alloc((size_t)2*HW_*2);
  float* qnormNeg = (float*)alloc((size_t)2*HW_*4);
  unsigned long long* packed = (unsigned long long*)alloc((size_t)2*HW_*8);
  float* raw      = (float*)alloc((size_t)2049*HW_*4);

  hipMemsetAsync(packed, 0, (size_t)2*HW_*8, stream);
  transpose_w<<<384,256,0,stream>>>(q_w, qk_w, k_w, qT, qkT, kT);
  gemm_hidden<<<dim3(132,2,2),256,0,stream>>>(feats, qT, q_b, hidden);
  gemm_small<0><<<dim3(132,2),256,0,stream>>>(hidden, qkT, qk_b, q16, fa2h, qnormNeg);
  gemm_small<1><<<dim3(132,2),256,0,stream>>>(feats, kT, k_b, k16, fb2h, nullptr);

  float* outF = (float*)d_out;
  float* corr = outF + PSM_SZ + RM_SZ;
  for (int pair = 0; pair < 2; pair++) {
    for (int stripe = 0; stripe < 5; stripe++) {
      int kbase = stripe*2048;
      int rows = (stripe < 4) ? 2048 : 256;
      corr_gemm<<<dim3(66, rows/128), 256, 0, stream>>>(q16, k16, fa2h, fb2h, raw, pair, kbase);
      int krows = (stripe < 4) ? 2048 : 257;
      if (stripe == 4) lastrow<<<33,256,0,stream>>>(qnormNeg, raw, pair, 256);
      int kchunks = (krows + KC_-1)/KC_;
      smooth_reduce<<<dim3(kchunks,12),256,0,stream>>>(raw, sm_w, sm_b, corr, packed, pair, kbase, krows);
    }
  }
  finalize<<<dim3(264,2),256,0,stream>>>(feats, packed, cls_w, cls_b, reg_w, reg_b, outF);
}

// Round 3
// 1378.441 us; speedup vs baseline: 1.6420x; 1.6420x over previous
//
#include <hip/hip_runtime.h>

#define H_ 48
#define W_ 176
#define HW_ 8448
#define K_ 8449
#define C_ 256
#define PSM_SZ 33792
#define RM_SZ 236544

typedef _Float16 f16x8 __attribute__((ext_vector_type(8)));
typedef float f32x4 __attribute__((ext_vector_type(4)));

__device__ inline float h2f_lo(unsigned u){ return (float)__builtin_bit_cast(_Float16,(unsigned short)(u&0xffff)); }
__device__ inline float h2f_hi(unsigned u){ return (float)__builtin_bit_cast(_Float16,(unsigned short)(u>>16)); }

// ---------------- weight transposes ----------------
__global__ void prep_w(const float* __restrict__ qw, const float* __restrict__ qkw,
                       const float* __restrict__ kw, float* __restrict__ qT,
                       float* __restrict__ qkT, float* __restrict__ kT) {
  int b = blockIdx.x, t = threadIdx.x;
  if (b < 256)      qT[t*256 + b]        = qw[b*256 + t];
  else if (b < 320) qkT[t*64 + (b-256)]  = qkw[(b-256)*256 + t];
  else              kT[t*64 + (b-320)]   = kw[(b-320)*256 + t];
}

// ---------------- feats [C][HW] -> featsT [HW][C], all 4 imgs ----------------
__global__ __launch_bounds__(256) void transpose_feats(
    const float* __restrict__ feats, float* __restrict__ featsT) {
  __shared__ float T[64][65];
  const int t = threadIdx.x;
  const int p0 = blockIdx.x*64, c0 = blockIdx.y*64, img = blockIdx.z;
  const int lane = t & 63, grp = t >> 6;
  const float* src = feats + (size_t)img*C_*HW_;
  #pragma unroll
  for (int i=0;i<16;i++)
    T[grp*16+i][lane] = src[(size_t)(c0+grp*16+i)*HW_ + p0+lane];
  __syncthreads();
  float* dst = featsT + (size_t)img*HW_*C_;
  #pragma unroll
  for (int i=0;i<16;i++)
    dst[(size_t)(p0+grp*16+i)*C_ + c0+lane] = T[lane][grp*16+i];
}

// ---------------- hidden = relu(q_w @ feat + q_b), imgs 0,2 ----------------
__global__ __launch_bounds__(256) void gemm_hidden(
    const float* __restrict__ feats, const float* __restrict__ qT,
    const float* __restrict__ qb, float* __restrict__ hidden) {
  __shared__ float ldsW[32*132];
  __shared__ float ldsF[32*64];
  const int t = threadIdx.x;
  const int px0 = blockIdx.x * 64;
  const int ob = blockIdx.y * 128;
  const int slot = blockIdx.z;
  const int img = slot * 2;
  const int pg = t & 15, og = t >> 4;
  float acc[32];
  #pragma unroll
  for (int z = 0; z < 32; z++) acc[z] = 0.f;
  const float* fbase = feats + (size_t)img*C_*HW_ + px0;
  for (int cb = 0; cb < 256; cb += 32) {
    for (int e = t; e < 2048; e += 256) {
      int cc = e >> 6, px = e & 63;
      ldsF[cc*64 + px] = fbase[(size_t)(cb+cc)*HW_ + px];
    }
    for (int e = t; e < 4096; e += 256) {
      int cc = e >> 7, o = e & 127;
      ldsW[cc*132 + o] = qT[(size_t)(cb+cc)*256 + ob + o];
    }
    __syncthreads();
    #pragma unroll 4
    for (int cc = 0; cc < 32; cc++) {
      f32x4 fv = *(const f32x4*)&ldsF[cc*64 + pg*4];
      f32x4 w0 = *(const f32x4*)&ldsW[cc*132 + og*8];
      f32x4 w1 = *(const f32x4*)&ldsW[cc*132 + og*8 + 4];
      #pragma unroll
      for (int p = 0; p < 4; p++) {
        float f = fv[p];
        #pragma unroll
        for (int q = 0; q < 4; q++) {
          acc[q*4+p]     += w0[q]*f;
          acc[(4+q)*4+p] += w1[q]*f;
        }
      }
    }
    __syncthreads();
  }
  float* hbase = hidden + (size_t)slot*C_*HW_;
  #pragma unroll
  for (int q = 0; q < 8; q++) {
    int o = ob + og*8 + q;
    float b = qb[o];
    f32x4 ov;
    #pragma unroll
    for (int p = 0; p < 4; p++) {
      float v = acc[q*4+p] + b;
      ov[p] = v > 0.f ? v : 0.f;
    }
    *(f32x4*)&hbase[(size_t)o*HW_ + px0 + pg*4] = ov;
  }
}

// ---------------- 64-out GEMM: MODE0 = qk (querys), MODE1 = keys ----------------
template<int MODE>
__global__ __launch_bounds__(256) void gemm_small(
    const float* __restrict__ inp, const float* __restrict__ wT,
    const float* __restrict__ bias, _Float16* __restrict__ out16,
    _Float16* __restrict__ f2h, float* __restrict__ qnormNeg) {
  __shared__ float ldsI[64*64];
  __shared__ float ldsW2[64*68];
  __shared__ float red16[64*16];
  __shared__ float red32[64*16];
  const int t = threadIdx.x;
  const int px0 = blockIdx.x*64;
  const int i = blockIdx.y;
  const float* ibase = (MODE==0) ? (inp + (size_t)i*C_*HW_ + px0)
                                 : (inp + (size_t)(1+2*i)*C_*HW_ + px0);
  const int pg = t & 15, jg = t >> 4;
  float acc[16];
  #pragma unroll
  for (int z=0;z<16;z++) acc[z]=0.f;
  for (int ob = 0; ob < 256; ob += 64) {
    for (int e=t; e<4096; e+=256) { int oc=e>>6, px=e&63; ldsI[oc*64+px]=ibase[(size_t)(ob+oc)*HW_+px]; }
    for (int e=t; e<4096; e+=256) { int oc=e>>6, j=e&63;  ldsW2[oc*68+j]=wT[(size_t)(ob+oc)*64+j]; }
    __syncthreads();
    #pragma unroll 4
    for (int oc=0; oc<64; oc++) {
      f32x4 iv = *(const f32x4*)&ldsI[oc*64+pg*4];
      f32x4 wv = *(const f32x4*)&ldsW2[oc*68+jg*4];
      #pragma unroll
      for (int j=0;j<4;j++)
        #pragma unroll
        for (int p=0;p<4;p++)
          acc[j*4+p] += wv[j]*iv[p];
    }
    __syncthreads();
  }
  const int j0 = jg*4;
  float s16[4] = {0,0,0,0};
  float s32[4] = {0,0,0,0};
  #pragma unroll
  for (int p=0;p<4;p++) {
    union { _Float16 h[4]; uint2 u; } uu;
    #pragma unroll
    for (int j=0;j<4;j++) {
      float v = acc[j*4+p] + bias[j0+j];
      if (MODE==1) v = v > 0.f ? v : 0.f;
      _Float16 h = (_Float16)v;
      uu.h[j] = h;
      _Float16 hh = h*h;
      s16[p] += (float)hh;
      if (MODE==0) s32[p] += v*v;
    }
    size_t pix = (size_t)i*HW_ + px0 + pg*4 + p;
    *(uint2*)&out16[pix*64 + j0] = uu.u;
  }
  #pragma unroll
  for (int p=0;p<4;p++) {
    red16[(pg*4+p)*16 + jg] = s16[p];
    if (MODE==0) red32[(pg*4+p)*16 + jg] = s32[p];
  }
  __syncthreads();
  if (t < 64) {
    float a16=0.f, a32=0.f;
    #pragma unroll
    for (int g=0; g<16; g++){ a16 += red16[t*16+g]; if (MODE==0) a32 += red32[t*16+g]; }
    f2h[(size_t)i*HW_ + px0 + t] = (_Float16)a16;
    if (MODE==0) qnormNeg[(size_t)i*HW_ + px0 + t] = -sqrtf(a32);
  }
}

// ---------------- corr volume GEMM -> raw f16 ----------------
__global__ __launch_bounds__(256) void corr_gemm(
    const _Float16* __restrict__ q16, const _Float16* __restrict__ k16,
    const _Float16* __restrict__ fa2h, const _Float16* __restrict__ fb2h,
    _Float16* __restrict__ raw, int pair, int kbase) {
  __shared__ _Float16 Kt[128*72];
  __shared__ _Float16 Qt[128*72];
  __shared__ _Float16 fa2s[128];
  __shared__ _Float16 fb2s[128];
  const int t = threadIdx.x;
  const int p0 = blockIdx.x*128;
  const int k0 = kbase + blockIdx.y*128;
  const _Float16* qb = q16 + ((size_t)pair*HW_ + p0)*64;
  const _Float16* kb = k16 + ((size_t)pair*HW_ + k0)*64;
  for (int e=t; e<1024; e+=256) {
    int row = e>>3, c8 = e&7;
    *(f16x8*)&Kt[row*72 + c8*8] = *(const f16x8*)&kb[(size_t)row*64 + c8*8];
    *(f16x8*)&Qt[row*72 + c8*8] = *(const f16x8*)&qb[(size_t)row*64 + c8*8];
  }
  if (t<128) { fa2s[t] = fa2h[(size_t)pair*HW_ + p0 + t];
               fb2s[t] = fb2h[(size_t)pair*HW_ + k0 + t]; }
  __syncthreads();
  const int w = t>>6, lane = t&63;
  const int wr = w>>1, wc = w&1;
  const int lr = lane&15, lk = lane>>4;
  f32x4 acc[4][4];
  #pragma unroll
  for (int m=0;m<4;m++)
    #pragma unroll
    for (int n=0;n<4;n++) acc[m][n] = (f32x4){0.f,0.f,0.f,0.f};
  #pragma unroll
  for (int ks=0; ks<2; ks++){
    f16x8 af[4], bf[4];
    #pragma unroll
    for (int m=0;m<4;m++) af[m] = *(const f16x8*)&Kt[(wr*64+m*16+lr)*72 + ks*32 + lk*8];
    #pragma unroll
    for (int n=0;n<4;n++) bf[n] = *(const f16x8*)&Qt[(wc*64+n*16+lr)*72 + ks*32 + lk*8];
    #pragma unroll
    for (int m=0;m<4;m++)
      #pragma unroll
      for (int n=0;n<4;n++)
        acc[m][n] = __builtin_amdgcn_mfma_f32_16x16x32_f16(af[m], bf[n], acc[m][n], 0,0,0);
  }
  #pragma unroll
  for (int m=0;m<4;m++){
    #pragma unroll
    for (int n=0;n<4;n++){
      int colL = wc*64 + n*16 + lr;
      _Float16 fa2 = fa2s[colL];
      #pragma unroll
      for (int r=0;r<4;r++){
        int rowL = wr*64 + m*16 + lk*4 + r;
        _Float16 fb2 = fb2s[rowL];
        _Float16 dh = (_Float16)acc[m][n][r];
        _Float16 d2 = (_Float16)(fa2 + fb2) - (_Float16)((_Float16)2.0f * dh);
        if (d2 < (_Float16)0.f) d2 = (_Float16)0.f;
        _Float16 sh = (_Float16)sqrtf((float)d2);
        raw[(size_t)(k0 - kbase + rowL)*HW_ + p0 + colL] = -sh;
      }
    }
  }
}

// ---------------- depthwise 3x3 + bias + corr write + argmax (k < HW) ----------------
#define KC_ 16
__global__ __launch_bounds__(256) void smooth_reduce(
    const _Float16* __restrict__ raw, const float* __restrict__ smw,
    const float* __restrict__ smb, float* __restrict__ outCorr,
    unsigned long long* __restrict__ packed, int pair, int kbase) {
  __shared__ _Float16 L[KC_][1060];
  __shared__ float SW[KC_][9];
  __shared__ float SB[KC_];
  const int t = threadIdx.x;
  const int kl0 = blockIdx.x * KC_;
  const int h0 = blockIdx.y * 4;
  const int p2start = (h0-1)*88;
  for (int kk=0; kk<KC_; kk++){
    const unsigned* rr = (const unsigned*)(raw + (size_t)(kl0+kk)*HW_);
    unsigned* Ld = (unsigned*)&L[kk][0];
    for (int e=t; e<528; e+=256){
      int p2 = p2start + e;
      unsigned v = 0u;
      if (p2 >= 0 && p2 < 4224) v = rr[p2];
      Ld[e] = v;
    }
  }
  if (t < KC_*9){
    int kk = t/9, e = t%9;
    SW[kk][e] = smw[(size_t)(kbase + kl0 + kk)*9 + e];
  }
  if (t < KC_) SB[t] = smb[kbase + kl0 + t];
  __syncthreads();
  float* ob = outCorr + (size_t)pair*K_*HW_;
  unsigned long long* pk = packed + (size_t)pair*HW_;
  for (int pp = t; pp < 352; pp += 256){
    const int hh = pp/88, xp = pp%88;
    const int x0 = xp*2;
    const int p = (h0+hh)*W_ + x0;
    unsigned long long best0 = 0, best1 = 0;
    for (int kk=0; kk<KC_; kk++){
      const unsigned* Lr = (const unsigned*)&L[kk][0];
      const float* sw = SW[kk];
      float ys0 = 0.f, ys1 = 0.f;
      #pragma unroll
      for (int r=0;r<3;r++){
        int bi = (hh+r)*88 + xp;
        unsigned u1 = Lr[bi];
        unsigned u2 = Lr[bi+1];
        float c1lo = h2f_lo(u1), c1hi = h2f_hi(u1);
        float w0 = sw[r*3], w1 = sw[r*3+1], w2 = sw[r*3+2];
        ys0 += c1lo*w1 + c1hi*w2;
        ys1 += c1lo*w0 + c1hi*w1;
        if (xp > 0)  ys0 += h2f_hi(Lr[bi-1])*w0;
        if (xp < 87) ys1 += h2f_lo(u2)*w2;
      }
      float val0 = ys0 + SB[kk];
      float val1 = ys1 + SB[kk];
      int kg = kbase + kl0 + kk;
      *(float2*)&ob[(size_t)kg*HW_ + p] = make_float2(val0, val1);
      unsigned ua = __float_as_uint(val0);
      ua = (ua & 0x80000000u) ? ~ua : (ua | 0x80000000u);
      unsigned long long ca = ((unsigned long long)ua << 32) | (unsigned)(0xFFFFFFFFu - (unsigned)kg);
      if (ca > best0) best0 = ca;
      unsigned ub = __float_as_uint(val1);
      ub = (ub & 0x80000000u) ? ~ub : (ub | 0x80000000u);
      unsigned long long cb = ((unsigned long long)ub << 32) | (unsigned)(0xFFFFFFFFu - (unsigned)kg);
      if (cb > best1) best1 = cb;
    }
    atomicMax(&pk[p], best0);
    atomicMax(&pk[p+1], best1);
  }
}

// ---------------- last channel (k = HW): f32 path from qnormNeg ----------------
__global__ __launch_bounds__(256) void last_smooth(
    const float* __restrict__ qn, const float* __restrict__ smw,
    const float* __restrict__ smb, float* __restrict__ outCorr,
    unsigned long long* __restrict__ packed) {
  const int p = blockIdx.x*256 + threadIdx.x;
  const int pair = blockIdx.y;
  if (p >= HW_) return;
  const int hh = p / W_, ww = p % W_;
  const float* q = qn + (size_t)pair*HW_;
  float ys = 0.f;
  #pragma unroll
  for (int r=-1;r<=1;r++){
    int y = hh + r;
    if (y < 0 || y >= H_) continue;
    #pragma unroll
    for (int c=-1;c<=1;c++){
      int x = ww + c;
      if (x < 0 || x >= W_) continue;
      ys += q[y*W_ + x] * smw[(size_t)(K_-1)*9 + (r+1)*3 + (c+1)];
    }
  }
  float val = ys + smb[K_-1];
  outCorr[(size_t)pair*K_*HW_ + (size_t)(K_-1)*HW_ + p] = val;
  unsigned u = __float_as_uint(val);
  u = (u & 0x80000000u) ? ~u : (u | 0x80000000u);
  unsigned long long cand = ((unsigned long long)u << 32) | (unsigned)(0xFFFFFFFFu - (unsigned)(K_-1));
  atomicMax(&packed[(size_t)pair*HW_ + p], cand);
}

// ---------------- grid_sample (transposed gather) + fuse-max + psm/rm ----------------
__global__ __launch_bounds__(256) void finalize(
    const float* __restrict__ featsT, const unsigned long long* __restrict__ packed,
    const float* __restrict__ clsw, const float* __restrict__ clsb,
    const float* __restrict__ regw, const float* __restrict__ regb,
    float* __restrict__ out) {
  __shared__ float fuse[256][33];
  __shared__ float wS[16][256];
  __shared__ int tapO[4][32];
  __shared__ float tapW[4][32];
  __shared__ float wmulS[32];
  const int t = threadIdx.x;
  const int b = blockIdx.y;
  const int px0 = blockIdx.x*32;
  for (int e=t; e<4096; e+=256){
    int a = e>>8, c = e&255;
    wS[a][c] = (a<2) ? clsw[a*256+c] : regw[(a-2)*256+c];
  }
  if (t < 32) {
    int p = px0 + t;
    unsigned long long pkv = packed[(size_t)b*HW_ + p];
    unsigned u = (unsigned)(pkv >> 32);
    unsigned fbits = (u & 0x80000000u) ? (u ^ 0x80000000u) : ~u;
    float weight = __uint_as_float(fbits);
    int kg = (int)(0xFFFFFFFFu - (unsigned)(pkv & 0xFFFFFFFFu));
    bool mask = (kg == K_-1);
    int xi = mask ? 0 : (kg % W_);
    int yi = mask ? 0 : (kg / W_);
    float xn = 2.0f*((float)xi/176.0f - 0.5f);
    float yn = 2.0f*((float)yi/48.0f - 0.5f);
    float gx = (xn + 1.0f)*88.0f - 0.5f;
    float gy = (yn + 1.0f)*24.0f - 0.5f;
    float x0f = floorf(gx), y0f = floorf(gy);
    float wx = gx - x0f, wy = gy - y0f;
    int x0 = (int)x0f, y0 = (int)y0f;
    int ix[4] = {x0, x0+1, x0, x0+1};
    int iy[4] = {y0, y0, y0+1, y0+1};
    float tw[4] = {(1.f-wx)*(1.f-wy), wx*(1.f-wy), (1.f-wx)*wy, wx*wy};
    #pragma unroll
    for (int q=0;q<4;q++){
      bool valid = (ix[q]>=0 && ix[q]<W_ && iy[q]>=0 && iy[q]<H_);
      int cx = min(max(ix[q],0),W_-1), cy = min(max(iy[q],0),H_-1);
      tapO[q][t] = cy*W_ + cx;
      tapW[q][t] = valid ? tw[q] : 0.f;
    }
    wmulS[t] = mask ? weight : 0.f;
  }
  __syncthreads();
  const float* fAT = featsT + (size_t)(2*b)*HW_*C_;
  const float* fBT = featsT + (size_t)(2*b+1)*HW_*C_;
  const int lane = t & 63, warp = t >> 6;
  const int ch = warp*64 + lane;
  for (int i=0;i<32;i++){
    int p = px0 + i;
    float v = fBT[(size_t)tapO[0][i]*C_ + ch]*tapW[0][i]
            + fBT[(size_t)tapO[1][i]*C_ + ch]*tapW[1][i]
            + fBT[(size_t)tapO[2][i]*C_ + ch]*tapW[2][i]
            + fBT[(size_t)tapO[3][i]*C_ + ch]*tapW[3][i];
    float a = fAT[(size_t)p*C_ + ch];
    fuse[ch][i] = fmaxf(a, v*wmulS[i]);
  }
  __syncthreads();
  const int px = t & 31, og = t >> 5;
  const int A0 = og*2, A1 = og*2+1;
  float a0 = 0.f, a1 = 0.f;
  for (int c=0;c<256;c++) {
    float f = fuse[c][px];
    a0 += f * wS[A0][c];
    a1 += f * wS[A1][c];
  }
  const int p = px0 + px;
  #pragma unroll
  for (int r=0;r<2;r++) {
    int a = og*2 + r;
    float v = (r==0?a0:a1) + ((a<2)? clsb[a] : regb[a-2]);
    size_t dst = (a<2) ? ((size_t)b*2*HW_ + (size_t)a*HW_ + p)
                       : ((size_t)PSM_SZ + (size_t)b*14*HW_ + (size_t)(a-2)*HW_ + p);
    out[dst] = v;
  }
}

// ---------------- launch ----------------
extern "C" void kernel_launch(void* const* d_in, const int* in_sizes, int n_in,
                              void* d_out, int out_size, void* d_ws, size_t ws_size,
                              hipStream_t stream) {
  const float* feats = (const float*)d_in[0];
  const float* q_w  = (const float*)d_in[1];
  const float* q_b  = (const float*)d_in[2];
  const float* qk_w = (const float*)d_in[3];
  const float* qk_b = (const float*)d_in[4];
  const float* k_w  = (const float*)d_in[5];
  const float* k_b  = (const float*)d_in[6];
  const float* sm_w = (const float*)d_in[7];
  const float* sm_b = (const float*)d_in[8];
  const float* cls_w= (const float*)d_in[9];
  const float* cls_b= (const float*)d_in[10];
  const float* reg_w= (const float*)d_in[11];
  const float* reg_b= (const float*)d_in[12];

  char* wp = (char*)d_ws;
  auto alloc = [&](size_t bytes) { char* r = wp; wp += (bytes + 255) & ~(size_t)255; return r; };
  float* hidden   = (float*)alloc((size_t)2*C_*HW_*4);
  float* featsT   = (float*)alloc((size_t)4*C_*HW_*4);
  float* qT       = (float*)alloc((size_t)256*256*4);
  float* qkT      = (float*)alloc((size_t)256*64*4);
  float* kT       = (float*)alloc((size_t)256*64*4);
  _Float16* q16   = (_Float16*)alloc((size_t)2*HW_*64*2);
  _Float16* k16   = (_Float16*)alloc((size_t)2*HW_*64*2);
  _Float16* fa2h  = (_Float16*)alloc((size_t)2*HW_*2);
  _Float16* fb2h  = (_Float16*)alloc((size_t)2*HW_*2);
  float* qnormNeg = (float*)alloc((size_t)2*HW_*4);
  unsigned long long* packed = (unsigned long long*)alloc((size_t)2*HW_*8);
  _Float16* raw   = (_Float16*)alloc((size_t)2048*HW_*2);

  hipMemsetAsync(packed, 0, (size_t)2*HW_*8, stream);
  prep_w<<<384,256,0,stream>>>(q_w, qk_w, k_w, qT, qkT, kT);
  transpose_feats<<<dim3(132,4,4),256,0,stream>>>(feats, featsT);
  gemm_hidden<<<dim3(132,2,2),256,0,stream>>>(feats, qT, q_b, hidden);
  gemm_small<0><<<dim3(132,2),256,0,stream>>>(hidden, qkT, qk_b, q16, fa2h, qnormNeg);
  gemm_small<1><<<dim3(132,2),256,0,stream>>>(feats, kT, k_b, k16, fb2h, nullptr);

  float* outF = (float*)d_out;
  float* corr = outF + PSM_SZ + RM_SZ;
  last_smooth<<<dim3(33,2),256,0,stream>>>(qnormNeg, sm_w, sm_b, corr, packed);
  for (int pair = 0; pair < 2; pair++) {
    for (int stripe = 0; stripe < 5; stripe++) {
      int kbase = stripe*2048;
      int rows = (stripe < 4) ? 2048 : 256;
      corr_gemm<<<dim3(66, rows/128), 256, 0, stream>>>(q16, k16, fa2h, fb2h, raw, pair, kbase);
      smooth_reduce<<<dim3(rows/KC_,12),256,0,stream>>>(raw, sm_w, sm_b, corr, packed, pair, kbase);
    }
  }
  finalize<<<dim3(264,2),256,0,stream>>>(featsT, packed, cls_w, cls_b, reg_w, reg_b, outF);
}